// Round 14
// baseline (406.768 us; speedup 1.0000x reference)
//
#include <hip/hip_runtime.h>
#include <math.h>

#define N_TOK 2000
#define NH 8
#define HD 32
#define SCALE 25.0f
#define SIM_TH 0.75f
#define EPSF 1e-8f
#define NSLOT 8   // ceil(2000/256)
#define NTAIL 208 // valid lanes in slot 7: 2000 - 7*256
#define SPAD 2048 // padded s_attn stride

typedef _Float16 half2_t __attribute__((ext_vector_type(2)));

__device__ __forceinline__ unsigned rflu(unsigned u) {
  return (unsigned)__builtin_amdgcn_readfirstlane((int)u);
}
__device__ __forceinline__ half2_t u2h(unsigned u) {
  return __builtin_bit_cast(half2_t, u);
}

// f32 += f16x2 . f16x2 (v_dot2_f32_f16; products exact, fp32 accumulate)
__device__ __forceinline__ float fdot2f(unsigned a, unsigned b, float c) {
#if __has_builtin(__builtin_amdgcn_fdot2)
  return __builtin_amdgcn_fdot2(u2h(a), u2h(b), c, false);
#else
  const half2_t ha = u2h(a), hb = u2h(b);
  return c + (float)ha.x * (float)hb.x + (float)ha.y * (float)hb.y;
#endif
}

// packed 4-value block reductions (2 syncs each)
__device__ __forceinline__ void block_sum4(float* v, float* red16) {
#pragma unroll
  for (int off = 32; off > 0; off >>= 1) {
#pragma unroll
    for (int q = 0; q < 4; q++) v[q] += __shfl_xor(v[q], off, 64);
  }
  __syncthreads();
  const int wid = threadIdx.x >> 6;
  if ((threadIdx.x & 63) == 0) {
#pragma unroll
    for (int q = 0; q < 4; q++) red16[wid * 4 + q] = v[q];
  }
  __syncthreads();
#pragma unroll
  for (int q = 0; q < 4; q++) {
    v[q] = (red16[q] + red16[4 + q]) + (red16[8 + q] + red16[12 + q]);
  }
}
__device__ __forceinline__ void block_max4(float* v, float* red16) {
#pragma unroll
  for (int off = 32; off > 0; off >>= 1) {
#pragma unroll
    for (int q = 0; q < 4; q++) v[q] = fmaxf(v[q], __shfl_xor(v[q], off, 64));
  }
  __syncthreads();
  const int wid = threadIdx.x >> 6;
  if ((threadIdx.x & 63) == 0) {
#pragma unroll
    for (int q = 0; q < 4; q++) red16[wid * 4 + q] = v[q];
  }
  __syncthreads();
#pragma unroll
  for (int q = 0; q < 4; q++) {
    v[q] = fmaxf(fmaxf(red16[q], red16[4 + q]),
                 fmaxf(red16[8 + q], red16[12 + q]));
  }
}

// ---------------------------------------------------------------------------
// Kernel 1: QKV projection + l2norm; 8 rows/block (W re-reads halved vs r13).
// f16 normalized planes [h][gg=d/8][n][8] + fp32 v_rm row-major.
// grid = (250, 2), block = 256
// ---------------------------------------------------------------------------
__global__ __launch_bounds__(256) void qkv_norm_kernel(
    const float* __restrict__ x_cls, const float* __restrict__ x_reg,
    const float* __restrict__ W_cls, const float* __restrict__ W_reg,
    _Float16* __restrict__ qc_h, _Float16* __restrict__ qr_h,
    _Float16* __restrict__ kc_h, _Float16* __restrict__ kr_h,
    _Float16* __restrict__ vn_h, float* __restrict__ v_rm) {
  __shared__ float xs[8][256];
  __shared__ float res[8][768];
  __shared__ float inv_norm[192];

  const int n0 = blockIdx.x * 8;
  const int which = blockIdx.y;
  const int tid = threadIdx.x;
  const float* __restrict__ x = which ? x_reg : x_cls;
  const float* __restrict__ W = which ? W_reg : W_cls;

#pragma unroll
  for (int r = 0; r < 8; r++) xs[r][tid] = x[(n0 + r) * 256 + tid];
  __syncthreads();

  float acc[8][3];
#pragma unroll
  for (int r = 0; r < 8; r++) acc[r][0] = acc[r][1] = acc[r][2] = 0.f;

  for (int k = 0; k < 256; k++) {
    const float* __restrict__ wr = W + k * 768;
    const float w0 = wr[tid], w1 = wr[tid + 256], w2 = wr[tid + 512];
#pragma unroll
    for (int r = 0; r < 8; r++) {
      const float xv = xs[r][k];
      acc[r][0] += xv * w0;
      acc[r][1] += xv * w1;
      acc[r][2] += xv * w2;
    }
  }
#pragma unroll
  for (int r = 0; r < 8; r++) {
    res[r][tid] = acc[r][0];
    res[r][tid + 256] = acc[r][1];
    res[r][tid + 512] = acc[r][2];
  }
  __syncthreads();

  if (tid < 192) {
    const int r = tid / 24, grp = tid % 24;
    float ss = 0.f;
#pragma unroll
    for (int d = 0; d < HD; d++) {
      const float v = res[r][grp * 32 + d];
      ss += v * v;
    }
    inv_norm[tid] = 1.0f / (sqrtf(ss) + EPSF);
  }
  __syncthreads();

#pragma unroll
  for (int j = 0; j < 3; j++) {
    const int c = tid + j * 256;
    const int qkv = c >> 8, grp = c >> 5;
    const int h = grp & 7, d = c & 31;
    const int gg = d >> 3, dd = d & 7;
#pragma unroll
    for (int r = 0; r < 8; r++) {
      const int n = n0 + r;
      const float val = res[r][c];
      const float nval = val * inv_norm[r * 24 + grp];
      const size_t fi = ((size_t)(h * 4 + gg) * N_TOK + n) * 8 + dd;
      if (qkv == 0) {
        (which ? qr_h : qc_h)[fi] = (_Float16)nval;
      } else if (qkv == 1) {
        (which ? kr_h : kc_h)[fi] = (_Float16)nval;
      } else if (which == 0) {
        v_rm[(h * N_TOK + n) * HD + d] = val;
        vn_h[fi] = (_Float16)nval;
      }
    }
  }
}

// ---------------------------------------------------------------------------
// Kernel 2: TQ=4 — four query rows per block (grid 500). Halves all stream
// traffic vs round 13 (5.1 -> 2.56 TB). Same 8-slot, 4+4 double-buffered
// sweep discipline (spill-safe shape); 64 fdot2 per 4-load kv batch.
// LDS: s_attn[4][2048] 32KB + s_er[4][2000]/part4 union 32KB -> 2 blocks/CU.
// Numerics identical to round 13 (same per-query arithmetic & order).
// grid = 500, block = 256
// ---------------------------------------------------------------------------
__global__ __launch_bounds__(256) void attn14_kernel(
    const _Float16* __restrict__ qc_h, const _Float16* __restrict__ qr_h,
    const _Float16* __restrict__ kc_h, const _Float16* __restrict__ kr_h,
    const _Float16* __restrict__ vn_h, const float* __restrict__ v_rm,
    float* __restrict__ out_x, float* __restrict__ out_sim) {
  __shared__ float s_attn[4][SPAD];  // 32 KB; tails stay 0 for PV
  __shared__ float s_union[8000];    // 32 KB: er[4][2000] / part4 (stride 9)
  __shared__ float red[16];

  float* __restrict__ s_er = s_union;
  float4* __restrict__ part4 = (float4*)s_union;

  const int tid = threadIdx.x;
  const int i0 = blockIdx.x * 4;
  int bsq[4];
#pragma unroll
  for (int q = 0; q < 4; q++) bsq[q] = ((i0 + q) / 10) * 10;

  float sim[4][NSLOT], raw[4][NSLOT];
#pragma unroll
  for (int q = 0; q < 4; q++) {
#pragma unroll
    for (int t = 0; t < NSLOT; t++) { sim[q][t] = 0.f; raw[q][t] = 0.f; }
  }
  if (tid < SPAD - N_TOK) {
#pragma unroll
    for (int q = 0; q < 4; q++) s_attn[q][N_TOK + tid] = 0.f;
  }
  __syncthreads();

  unsigned qp[4][16];  // packed f16 query quad, wave-uniform

  // load a query quad's packed-f16 rows into uniform uints
  auto load_qquad = [&](const _Float16* buf, int h) {
    const uint4* __restrict__ qb = (const uint4*)buf + (size_t)h * 4 * N_TOK;
#pragma unroll
    for (int q = 0; q < 4; q++) {
#pragma unroll
      for (int gg = 0; gg < 4; gg++) {
        const uint4 a = qb[gg * N_TOK + (i0 + q)];
        qp[q][4 * gg + 0] = rflu(a.x);
        qp[q][4 * gg + 1] = rflu(a.y);
        qp[q][4 * gg + 2] = rflu(a.z);
        qp[q][4 * gg + 3] = rflu(a.w);
      }
    }
  };

  // pipelined sweep: 4+4 double-buffered kv; 64 fdot2 per batch; emit(t,d[4])
  auto sweep = [&](const uint4* __restrict__ kt4, auto&& emit) {
    uint4 ka[4], kb[4];
#pragma unroll
    for (int g_ = 0; g_ < 4; g_++) ka[g_] = kt4[g_ * N_TOK + tid];  // t=0
#pragma unroll
    for (int t = 0; t < NSLOT; t++) {
      if (t < NSLOT - 1) {
        const int m1 = tid + 256 * (t + 1);
        const bool v1 = (t + 1 < 7) || (tid < NTAIL);
        const int mc1 = v1 ? m1 : (N_TOK - 1);
#pragma unroll
        for (int g_ = 0; g_ < 4; g_++) kb[g_] = kt4[g_ * N_TOK + mc1];
      }
      float d[4] = {0.f, 0.f, 0.f, 0.f};
#pragma unroll
      for (int g_ = 0; g_ < 4; g_++) {
#pragma unroll
        for (int q = 0; q < 4; q++) {
          d[q] = fdot2f(ka[g_].x, qp[q][4 * g_ + 0], d[q]);
          d[q] = fdot2f(ka[g_].y, qp[q][4 * g_ + 1], d[q]);
          d[q] = fdot2f(ka[g_].z, qp[q][4 * g_ + 2], d[q]);
          d[q] = fdot2f(ka[g_].w, qp[q][4 * g_ + 3], d[q]);
        }
      }
      emit(t, d);
#pragma unroll
      for (int g_ = 0; g_ < 4; g_++) ka[g_] = kb[g_];
    }
  };

  for (int hh = 0; hh < NH; hh++) {
    const int h = (blockIdx.x + hh) & 7;  // XCD-local head schedule

    // ===== phase C: cls scores -> e = exp(s-25) -> s_attn + running sums ===
    load_qquad(qc_h, h);
    float ls[4] = {0.f, 0.f, 0.f, 0.f};
    sweep((const uint4*)kc_h + (size_t)h * 4 * N_TOK,
          [&](int t, float* d) {
            const int m = tid + 256 * t;
            const bool valid = (t < 7) || (tid < NTAIL);
#pragma unroll
            for (int q = 0; q < 4; q++) {
              const float e = valid ? __expf(d[q] * SCALE - SCALE) : 0.f;
              ls[q] += e;
              if (valid) s_attn[q][m] = e;
            }
          });
    block_sum4(ls, red);
    float nc[4];
#pragma unroll
    for (int q = 0; q < 4; q++) nc[q] = 0.5f / ls[q];

    // ===== phase R: reg scores -> s_er + running sums =====
    load_qquad(qr_h, h);
    float lr[4] = {0.f, 0.f, 0.f, 0.f};
    sweep((const uint4*)kr_h + (size_t)h * 4 * N_TOK,
          [&](int t, float* d) {
            const int m = tid + 256 * t;
            const bool valid = (t < 7) || (tid < NTAIL);
#pragma unroll
            for (int q = 0; q < 4; q++) {
              const float e = valid ? __expf(d[q] * SCALE - SCALE) : 0.f;
              lr[q] += e;
              if (valid) s_er[q * N_TOK + m] = e;
            }
          });
    block_sum4(lr, red);
    float nr[4];
#pragma unroll
    for (int q = 0; q < 4; q++) nr[q] = 0.5f / lr[q];

    // ===== combine, mask, sim += =====
#pragma unroll
    for (int t = 0; t < NSLOT; t++) {
      const int m = tid + 256 * t;
      if ((t < 7) || (tid < NTAIL)) {
#pragma unroll
        for (int q = 0; q < 4; q++) {
          float a = s_attn[q][m] * nc[q] + s_er[q * N_TOK + m] * nr[q];
          if (m >= bsq[q] && m < bsq[q] + 9 && m != i0 + q) a = 0.f;
          s_attn[q][m] = a;
          sim[q][t] += a;
        }
      }
    }

    // ===== phase V: vn cosine -> raw += =====
    load_qquad(vn_h, h);
    sweep((const uint4*)vn_h + (size_t)h * 4 * N_TOK,
          [&](int t, float* d) {
            const bool valid = (t < 7) || (tid < NTAIL);
            if (valid) {
#pragma unroll
              for (int q = 0; q < 4; q++) raw[q][t] += d[q];
            }
          });
    __syncthreads();  // s_attn final; s_er reads done -> part4 may reuse

    // ===== attn @ V : fp32 V, 4 queries share each v4 load; rotated m-order
    {
      const int g2 = tid & 7, slice = tid >> 3;
      const int m0 = slice * 64;
      float4 acc[4];
#pragma unroll
      for (int q = 0; q < 4; q++) acc[q] = (float4){0.f, 0.f, 0.f, 0.f};
      const float4* __restrict__ v4 = (const float4*)v_rm + (size_t)h * N_TOK * 8;
#pragma unroll 4
      for (int j = 0; j < 16; j++) {
        const int m = m0 + 4 * ((j + slice) & 15);  // bank-disjoint slices
        float4 av[4];
#pragma unroll
        for (int q = 0; q < 4; q++) av[q] = *(const float4*)&s_attn[q][m];
        // pad rows (m>=2000) have a==0; OOB v4 reads stay inside d_ws (f16
        // plane bytes cannot alias to f32 NaN/Inf).
        const float4 vv0 = v4[(size_t)(m + 0) * 8 + g2];
        const float4 vv1 = v4[(size_t)(m + 1) * 8 + g2];
        const float4 vv2 = v4[(size_t)(m + 2) * 8 + g2];
        const float4 vv3 = v4[(size_t)(m + 3) * 8 + g2];
#pragma unroll
        for (int q = 0; q < 4; q++) {
          acc[q].x += av[q].x * vv0.x; acc[q].y += av[q].x * vv0.y;
          acc[q].z += av[q].x * vv0.z; acc[q].w += av[q].x * vv0.w;
          acc[q].x += av[q].y * vv1.x; acc[q].y += av[q].y * vv1.y;
          acc[q].z += av[q].y * vv1.z; acc[q].w += av[q].y * vv1.w;
          acc[q].x += av[q].z * vv2.x; acc[q].y += av[q].z * vv2.y;
          acc[q].z += av[q].z * vv2.z; acc[q].w += av[q].z * vv2.w;
          acc[q].x += av[q].w * vv3.x; acc[q].y += av[q].w * vv3.y;
          acc[q].z += av[q].w * vv3.z; acc[q].w += av[q].w * vv3.w;
        }
      }
#pragma unroll
      for (int q = 0; q < 4; q++) {
        part4[(slice * 4 + q) * 9 + g2] = acc[q];
      }
    }
    __syncthreads();
    if (tid < 32) {
      const int q = tid >> 3, g = tid & 7;
      float4 s = {0.f, 0.f, 0.f, 0.f};
#pragma unroll 8
      for (int sl = 0; sl < 32; sl++) {
        const float4 p = part4[(sl * 4 + q) * 9 + g];
        s.x += p.x; s.y += p.y; s.z += p.z; s.w += p.w;
      }
      *(float4*)(out_x + (size_t)(i0 + q) * 512 + h * 32 + 4 * g) = s;
    } else if (tid >= 64 && tid < 192) {
      const int idx = tid - 64;
      const int q = idx >> 5, d = idx & 31;
      out_x[(size_t)(i0 + q) * 512 + 256 + h * 32 + d] =
          v_rm[((size_t)h * N_TOK + i0 + q) * HD + d];
    }
    __syncthreads();  // part4 reads done -> s_er/s_attn reuse next head
  }

  // ===== sim_round2 epilogue, packed 4-query reductions =====
  float lm[4] = {-1e30f, -1e30f, -1e30f, -1e30f};
#pragma unroll
  for (int t = 0; t < NSLOT; t++) {
    if ((t < 7) || (tid < NTAIL)) {
#pragma unroll
      for (int q = 0; q < 4; q++) lm[q] = fmaxf(lm[q], sim[q][t] * 0.125f);
    }
  }
  block_max4(lm, red);

  float ls[4] = {0.f, 0.f, 0.f, 0.f};
#pragma unroll
  for (int t = 0; t < NSLOT; t++) {
    const bool valid = (t < 7) || (tid < NTAIL);
#pragma unroll
    for (int q = 0; q < 4; q++) {
      const float e = valid ? __expf(sim[q][t] * 0.125f - lm[q]) : 0.f;
      sim[q][t] = e;
      ls[q] += e;
    }
  }
  block_sum4(ls, red);
  float invS[4];
#pragma unroll
  for (int q = 0; q < 4; q++) invS[q] = 1.0f / ls[q];

  float lms[4] = {0.f, 0.f, 0.f, 0.f};
#pragma unroll
  for (int t = 0; t < NSLOT; t++) {
    const bool valid = (t < 7) || (tid < NTAIL);
#pragma unroll
    for (int q = 0; q < 4; q++) {
      const float p = sim[q][t] * invS[q];
      const float mp = (valid && (raw[q][t] * 0.125f > SIM_TH)) ? p : 0.f;
      sim[q][t] = mp;
      lms[q] += mp;
    }
  }
  block_sum4(lms, red);
  float invMS[4];
#pragma unroll
  for (int q = 0; q < 4; q++) invMS[q] = 1.0f / (lms[q] + EPSF);

#pragma unroll
  for (int t = 0; t < NSLOT; t++) {
    const int m = tid + 256 * t;
    if ((t < 7) || (tid < NTAIL)) {
#pragma unroll
      for (int q = 0; q < 4; q++) {
        out_sim[(size_t)(i0 + q) * N_TOK + m] = sim[q][t] * invMS[q];
      }
    }
  }
}

// ---------------------------------------------------------------------------
extern "C" void kernel_launch(void* const* d_in, const int* in_sizes, int n_in,
                              void* d_out, int out_size, void* d_ws,
                              size_t ws_size, hipStream_t stream) {
  const float* x_cls = (const float*)d_in[0];
  const float* x_reg = (const float*)d_in[1];
  const float* W_cls = (const float*)d_in[2];
  const float* W_reg = (const float*)d_in[3];

  // ws layout: v_rm fp32 first (PV OOB-clamped reads land in f16 planes,
  // which cannot alias to f32 NaN), then five f16 plane buffers
  const size_t seg = (size_t)NH * N_TOK * HD;  // 512000 elements
  float* v_rm = (float*)d_ws;
  _Float16* qc_h = (_Float16*)(v_rm + seg);
  _Float16* qr_h = qc_h + seg;
  _Float16* kc_h = qr_h + seg;
  _Float16* kr_h = kc_h + seg;
  _Float16* vn_h = kr_h + seg;

  dim3 g1(250, 2);
  qkv_norm_kernel<<<g1, 256, 0, stream>>>(x_cls, x_reg, W_cls, W_reg, qc_h,
                                          qr_h, kc_h, kr_h, vn_h, v_rm);

  float* out_x = (float*)d_out;                  // [2000, 512]
  float* out_sim = out_x + (size_t)N_TOK * 512;  // [2000, 2000]
  attn14_kernel<<<500, 256, 0, stream>>>(qc_h, qr_h, kc_h, kr_h, vn_h, v_rm,
                                         out_x, out_sim);
}